// Round 13
// baseline (10607.813 us; speedup 1.0000x reference)
//
#include <hip/hip_runtime.h>
#include <math.h>

#define S_  256
#define B_  64
#define E_  512
#define H_  512
#define G4_ 2048   // 4*H
#define NL_ 4
#define E4_ 128    // H/4

typedef __attribute__((ext_vector_type(8))) _Float16 f16x8;
typedef __attribute__((ext_vector_type(4))) float f32x4;
typedef __attribute__((ext_vector_type(4))) unsigned u32x4;

#define CANARY_ 0x7C7C7C7Cu   // fp16 NaN pair; h = sigmoid*tanh can't be NaN

__device__ __forceinline__ float fsigmoid(float x) {
    return 1.0f / (1.0f + __expf(-x));
}
__device__ __forceinline__ float ftanh_(float x) {
    x = fminf(fmaxf(x, -15.0f), 15.0f);
    float e = __expf(2.0f * x);
    return (e - 1.0f) / (e + 1.0f);
}
__device__ __forceinline__ ushort f2h(float x) {      // RNE f32->fp16
    _Float16 h = (_Float16)x;
    return *(ushort*)&h;
}
__device__ __forceinline__ float h2f(ushort u) {
    _Float16 h = *(_Float16*)&u;
    return (float)h;
}

// ---------------------------------------------------------------------------
// h-slab layout (fp16):
//   hb[t][grp(8)][cc(16)][k(512)] half     grp = bblk*2 + dir; cc = b&15; k = j
// ---------------------------------------------------------------------------
#define SLAB_ ((size_t)16 * 512)          // halves per (t,grp)
__device__ __forceinline__ size_t slab_off(int t, int grp) {
    return (size_t)(t * 8 + grp) * SLAB_;
}

// ---------------------------------------------------------------------------
// Frag-order conversions (verified 16x16x32 maps):
//   A-frag: lane l -> row = base + (l&15), k = ks*32 + (l>>4)*8 + e
//   B-frag: lane l -> col = base + (l&15), same k map
// ---------------------------------------------------------------------------

// Wi fp32 [2048][512] -> WiF fp16 frag order (128 row tiles of 16)
__global__ __launch_bounds__(256) void wif_k(
    const float* __restrict__ Wi, ushort* __restrict__ WiF)
{
    int i = blockIdx.x * 256 + threadIdx.x;   // 131,072
    int nt = i >> 10, ks = (i >> 6) & 15, l = i & 63;
    int n = nt * 16 + (l & 15);
    int k = ks * 32 + ((l >> 4) << 3);
    const float* src = Wi + (size_t)n * E_ + k;
    float4 v0 = *(const float4*)src, v1 = *(const float4*)(src + 4);
    ushort o[8] = {f2h(v0.x), f2h(v0.y), f2h(v0.z), f2h(v0.w),
                   f2h(v1.x), f2h(v1.y), f2h(v1.z), f2h(v1.w)};
    *(ushort4*)(WiF + (size_t)i * 8)     = *(ushort4*)&o[0];
    *(ushort4*)(WiF + (size_t)i * 8 + 4) = *(ushort4*)&o[4];
}

// Wh fp32 -> WhF fp16, gate-interleaved rows r=(jloc<<2)|g (persist A order)
__global__ __launch_bounds__(256) void whf_k(
    const float* __restrict__ Wh, ushort* __restrict__ WhF)
{
    int i = blockIdx.x * 256 + threadIdx.x;       // 1,048,576
    int e = i & 7, l = (i >> 3) & 63, ks = (i >> 9) & 15;
    int w = (i >> 13) & 3, wgin = i >> 15;
    int r = l & 15, g = r & 3, j = wgin * 16 + w * 4 + (r >> 2);
    int k = ks * 32 + ((l >> 4) << 3) + e;
    WhF[i] = f2h(Wh[(size_t)(g * H_ + j) * H_ + k]);
}

// layer-0 input: x fp32 [16384][512] -> inF fp16 B-frag order
__global__ __launch_bounds__(256) void cvt_x_k(
    const float* __restrict__ x, ushort* __restrict__ inF)
{
    int i = blockIdx.x * 256 + threadIdx.x;   // 1,048,576
    int mt = i >> 10, ks = (i >> 6) & 15, l = i & 63;
    int m = mt * 16 + (l & 15);
    int k = ks * 32 + ((l >> 4) << 3);
    const float* src = x + (size_t)m * E_ + k;
    float4 v0 = *(const float4*)src, v1 = *(const float4*)(src + 4);
    ushort o[8] = {f2h(v0.x), f2h(v0.y), f2h(v0.z), f2h(v0.w),
                   f2h(v1.x), f2h(v1.y), f2h(v1.z), f2h(v1.w)};
    *(ushort4*)(inF + (size_t)i * 8)     = *(ushort4*)&o[0];
    *(ushort4*)(inF + (size_t)i * 8 + 4) = *(ushort4*)&o[4];
}

// layer>=1 input: inF = hsF + hsB from fp16 slabs
__global__ __launch_bounds__(256) void cvt_hs_k(
    const ushort* __restrict__ hb, ushort* __restrict__ inF)
{
    int i = blockIdx.x * 256 + threadIdx.x;   // 1,048,576
    int mt = i >> 10, ks = (i >> 6) & 15, l = i & 63;
    int m = mt * 16 + (l & 15);
    int k = ks * 32 + ((l >> 4) << 3);
    int t = m >> 6, b = m & 63, cc = b & 15, bb = b >> 4;
    const ushort* pF = hb + slab_off(t, bb * 2 + 0) + (size_t)cc * 512 + k;
    const ushort* pB = hb + slab_off(t, bb * 2 + 1) + (size_t)cc * 512 + k;
    ushort4 f0 = *(const ushort4*)pF, f1 = *(const ushort4*)(pF + 4);
    ushort4 b0 = *(const ushort4*)pB, b1 = *(const ushort4*)(pB + 4);
    ushort o[8] = {f2h(h2f(f0.x) + h2f(b0.x)), f2h(h2f(f0.y) + h2f(b0.y)),
                   f2h(h2f(f0.z) + h2f(b0.z)), f2h(h2f(f0.w) + h2f(b0.w)),
                   f2h(h2f(f1.x) + h2f(b1.x)), f2h(h2f(f1.y) + h2f(b1.y)),
                   f2h(h2f(f1.z) + h2f(b1.z)), f2h(h2f(f1.w) + h2f(b1.w))};
    *(ushort4*)(inF + (size_t)i * 8)     = *(ushort4*)&o[0];
    *(ushort4*)(inF + (size_t)i * 8 + 4) = *(ushort4*)&o[4];
}

// ---------------------------------------------------------------------------
// pre = Wi . in + bias via fp16 MFMA.  C[n(2048)][m(16384)], K=512.
// ---------------------------------------------------------------------------
__global__ __launch_bounds__(256) void gemm_mfma_k(
    const ushort* __restrict__ WiF,
    const ushort* __restrict__ inF,
    const float* __restrict__ bias,
    float* __restrict__ pre)
{
    const int tid = threadIdx.x;
    const int w   = tid >> 6;
    const int l   = tid & 63;
    const int nb  = blockIdx.x >> 6;
    const int mb  = blockIdx.x & 63;

    f32x4 acc[4][4];
#pragma unroll
    for (int i = 0; i < 4; ++i)
#pragma unroll
        for (int j = 0; j < 4; ++j) acc[i][j] = f32x4{0.f, 0.f, 0.f, 0.f};

    const ushort* aB = WiF + ((size_t)(nb * 4) * 16) * 512 + l * 8;
    const ushort* bB = inF + ((size_t)(mb * 16 + w * 4) * 16) * 512 + l * 8;

    for (int ks = 0; ks < 16; ++ks) {
        f16x8 af[4], bf[4];
#pragma unroll
        for (int i = 0; i < 4; ++i)
            af[i] = *(const f16x8*)(aB + ((size_t)i * 16 + ks) * 512);
#pragma unroll
        for (int j = 0; j < 4; ++j)
            bf[j] = *(const f16x8*)(bB + ((size_t)j * 16 + ks) * 512);
#pragma unroll
        for (int i = 0; i < 4; ++i)
#pragma unroll
            for (int j = 0; j < 4; ++j)
                acc[i][j] = __builtin_amdgcn_mfma_f32_16x16x32_f16(
                    af[i], bf[j], acc[i][j], 0, 0, 0);
    }

#pragma unroll
    for (int i = 0; i < 4; ++i) {
#pragma unroll
        for (int j = 0; j < 4; ++j) {
#pragma unroll
            for (int g = 0; g < 4; ++g) {
                int n = nb * 64 + i * 16 + ((l >> 4) << 2) + g;
                int m = mb * 256 + w * 64 + j * 16 + (l & 15);
                int t = m >> 6, b = m & 63;
                pre[((size_t)t * G4_ + n) * B_ + b] = acc[i][j][g] + bias[n];
            }
        }
    }
}

// ---------------------------------------------------------------------------
// Persistent recurrence v11: canary data-poll — the data IS the flag.
// hb pre-filled with 0x7C (fp16 NaN); h values can never be NaN-bit patterns.
// Per step per wave (fully independent, no LDS, no __syncthreads, no flags):
//   load pre C-in -> poll-load 16 B-frags (global_load_dwordx4 sc0 sc1 =
//   coherence-point, placement-independent) until no canary word -> 16 MFMAs
//   from registers -> lane-local gates/c -> fire-and-forget write-through
//   publish (4B pair per lane-pair, each address written once per layer).
// Critical path ~1.5 LLC RTs vs R12's ~3 RTs + 2 barriers.
// ---------------------------------------------------------------------------
__global__ __launch_bounds__(256, 1) void lstm_persist_k(
    const float* __restrict__ pre,    // [S][G4][B]
    const ushort* __restrict__ WhF,   // frag-ordered fp16 weights
    ushort* __restrict__ hb)          // h slabs [S][8][16][512] fp16, canaried
{
    const int tid  = threadIdx.x;
    const int grp  = blockIdx.x & 7;
    const int wgin = blockIdx.x >> 3;            // 0..31 j-slice
    const int dir  = grp & 1;
    const int bblk = grp >> 1;
    const int w    = tid >> 6;                   // wave
    const int l    = tid & 63;
    const int ch   = l & 15;
    const int jloc = l >> 4;                     // 0..3
    const int j    = wgin * 16 + w * 4 + jloc;
    const int b    = bblk * 16 + ch;

    const ushort* wbase = WhF + ((size_t)(wgin * 4 + w) << 13) + (l << 3);
    // B-frag lane offset in a slab: (l&15)*512 + (l>>4)*8 (+ ks*32 per slot)
    const int fragLane = (l & 15) * 512 + ((l >> 4) << 3);

    // preload this wave's weight slice
    f16x8 wF[16];
#pragma unroll
    for (int ks = 0; ks < 16; ++ks)
        wF[ks] = *(const f16x8*)(wbase + (ks << 9));

    float c = 0.0f;

    for (int t = 0; t < S_; ++t) {
#pragma unroll
        for (int ks = 0; ks < 16; ++ks)
            asm volatile("" : "+v"(wF[ks]));     // keep weights resident

        const int tf = dir ? (S_ - 1 - t) : t;

        // own (j,b) pre values -> MFMA C-in (issued before the poll)
        f32x4 acc;
#pragma unroll
        for (int g = 0; g < 4; ++g)
            acc[g] = pre[((size_t)tf * G4_ + g * H_ + j) * B_ + b];

        if (t > 0) {
            const int tfp = dir ? (tf + 1) : (tf - 1);
            const ushort* src = hb + slab_off(tfp, grp) + fragLane;

            // poll-load all 16 B-frags until no canary remains
            f16x8 u[16];
            unsigned guard = 0;
            for (;;) {
#pragma unroll
                for (int ks = 0; ks < 16; ++ks)
                    asm volatile("global_load_dwordx4 %0, %1, off sc0 sc1"
                                 : "=v"(u[ks]) : "v"(src + ks * 32));
                asm volatile("s_waitcnt vmcnt(0)" ::: "memory");
                __builtin_amdgcn_sched_barrier(0);   // rule #18: pin uses after wait
                unsigned dirty = 0;
#pragma unroll
                for (int ks = 0; ks < 16; ++ks) {
                    u32x4 v = __builtin_bit_cast(u32x4, u[ks]);
                    dirty |= (v[0] == CANARY_) | (v[1] == CANARY_) |
                             (v[2] == CANARY_) | (v[3] == CANARY_);
                }
                if (!__any(dirty)) break;
                if (++guard > (1u << 18)) break;     // fail visibly, don't hang
            }

            // 16 MFMAs over K=512, 2 interleaved chains, straight from regs
            f32x4 a1 = {0.f, 0.f, 0.f, 0.f};
#pragma unroll
            for (int ks = 0; ks < 16; ks += 2) {
                acc = __builtin_amdgcn_mfma_f32_16x16x32_f16(wF[ks], u[ks], acc, 0, 0, 0);
                a1  = __builtin_amdgcn_mfma_f32_16x16x32_f16(wF[ks + 1], u[ks + 1], a1, 0, 0, 0);
            }
#pragma unroll
            for (int g = 0; g < 4; ++g) acc[g] += a1[g];
        }

        // gates (order i,f,o,g), fully lane-local
        float si = fsigmoid(acc[0]);
        float sf = fsigmoid(acc[1]);
        float so = fsigmoid(acc[2]);
        float tg = ftanh_(acc[3]);
        c = fmaf(sf, c, si * tg);
        float h = so * ftanh_(c);

        // publish h fp16, k-pair packed via lane partner (jloc ^ 1);
        // fire-and-forget write-through (no drain needed: first-touch slots)
        unsigned hv = f2h(h);
        unsigned pv = (unsigned)__shfl_xor((int)hv, 16);   // partner lane l^16
        if ((jloc & 1) == 0) {
            unsigned pair = (hv & 0xFFFFu) | (pv << 16);
            unsigned* shW = (unsigned*)(hb + slab_off(tf, grp));
            __hip_atomic_store(&shW[(size_t)ch * 256 + (j >> 1)], pair,
                               __ATOMIC_RELAXED, __HIP_MEMORY_SCOPE_AGENT);
        }
    }
}

// out[t][b][e] = hF + hB from fp16 slabs
__global__ __launch_bounds__(256) void t4_to_row_k(
    const ushort* __restrict__ hb, float* __restrict__ out)
{
    int i  = blockIdx.x * 256 + threadIdx.x;   // 2,097,152 float4 units
    int e4 = i & (E4_ - 1);
    int b  = (i >> 7) & 63;
    int t  = i >> 13;
    int cc = b & 15, bb = b >> 4;
    size_t e = (size_t)cc * 512 + e4 * 4;
    ushort4 hF = *(const ushort4*)(hb + slab_off(t, bb * 2 + 0) + e);
    ushort4 hB = *(const ushort4*)(hb + slab_off(t, bb * 2 + 1) + e);
    float4 v = make_float4(h2f(hF.x) + h2f(hB.x), h2f(hF.y) + h2f(hB.y),
                           h2f(hF.z) + h2f(hB.z), h2f(hF.w) + h2f(hB.w));
    *(float4*)&out[((size_t)(t * B_ + b)) * E_ + e4 * 4] = v;
}

// tail [b][j] = h_fwd(tf=255) + h_bwd(tf=0)
__global__ __launch_bounds__(256) void tail_k(
    const ushort* __restrict__ hb, float* __restrict__ out2)
{
    int i = blockIdx.x * 256 + threadIdx.x;   // 32768
    int b = i >> 9, j = i & 511;
    int cc = b & 15, bb = b >> 4;
    ushort hF = hb[slab_off(255, bb * 2 + 0) + (size_t)cc * 512 + j];
    ushort hB = hb[slab_off(0,   bb * 2 + 1) + (size_t)cc * 512 + j];
    out2[i] = h2f(hF) + h2f(hB);
}

// ---------------------------------------------------------------------------
// Workspace (bytes):
//   pre : 128 MiB   hb : 32 MiB   WhF4 : 8 MiB   WiF4 : 8 MiB   inF : 16 MiB
// total 192 MiB
// ---------------------------------------------------------------------------
extern "C" void kernel_launch(void* const* d_in, const int* in_sizes, int n_in,
                              void* d_out, int out_size, void* d_ws, size_t ws_size,
                              hipStream_t stream) {
    const float* x    = (const float*)d_in[0];
    const float* Wi   = (const float*)d_in[1];
    const float* Wh   = (const float*)d_in[2];
    const float* bias = (const float*)d_in[3];
    float* out = (float*)d_out;

    float* ws  = (float*)d_ws;
    float* pre = ws;
    ushort* hb   = (ushort*)(pre + (size_t)S_ * G4_ * B_);   // 16.8M halves
    ushort* WhF4 = hb + (size_t)S_ * 8 * SLAB_;              // 4 x 1,048,576
    ushort* WiF4 = WhF4 + (size_t)4 * 1024 * 1024;           // 4 x 1,048,576
    ushort* inF  = WiF4 + (size_t)4 * 1024 * 1024;           // 8,388,608

    // one-time weight conversions (all layers)
    for (int l = 0; l < NL_; ++l) {
        whf_k<<<4096, 256, 0, stream>>>(Wh + (size_t)l * G4_ * H_,
                                        WhF4 + (size_t)l * 1024 * 1024);
        wif_k<<<512, 256, 0, stream>>>(Wi + (size_t)l * G4_ * E_,
                                       WiF4 + (size_t)l * 1024 * 1024);
    }

    for (int l = 0; l < NL_; ++l) {
        if (l == 0) cvt_x_k<<<4096, 256, 0, stream>>>(x, inF);
        else        cvt_hs_k<<<4096, 256, 0, stream>>>(hb, inF);
        gemm_mfma_k<<<2048, 256, 0, stream>>>(WiF4 + (size_t)l * 1024 * 1024,
                                              inF, bias + (size_t)l * G4_, pre);
        hipMemsetAsync(hb, 0x7C, (size_t)S_ * 8 * SLAB_ * sizeof(ushort), stream);
        lstm_persist_k<<<256, 256, 0, stream>>>(
            pre, WhF4 + (size_t)l * 1024 * 1024, hb);
    }
    t4_to_row_k<<<8192, 256, 0, stream>>>(hb, out);
    tail_k<<<128, 256, 0, stream>>>(hb, out + (size_t)S_ * B_ * H_);
}

// Round 14
// 5618.183 us; speedup vs baseline: 1.8881x; 1.8881x over previous
//
#include <hip/hip_runtime.h>
#include <math.h>

#define S_  256
#define B_  64
#define E_  512
#define H_  512
#define G4_ 2048   // 4*H
#define NL_ 4
#define E4_ 128    // H/4

typedef __attribute__((ext_vector_type(8))) _Float16 f16x8;
typedef __attribute__((ext_vector_type(4))) float f32x4;

__device__ __forceinline__ float fsigmoid(float x) {
    return 1.0f / (1.0f + __expf(-x));
}
__device__ __forceinline__ float ftanh_(float x) {
    x = fminf(fmaxf(x, -15.0f), 15.0f);
    float e = __expf(2.0f * x);
    return (e - 1.0f) / (e + 1.0f);
}
__device__ __forceinline__ ushort f2h(float x) {      // RNE f32->fp16
    _Float16 h = (_Float16)x;
    return *(ushort*)&h;
}
__device__ __forceinline__ float h2f(ushort u) {
    _Float16 h = *(_Float16*)&u;
    return (float)h;
}

// async global->LDS, 16B per lane (lane i lands at lptr + i*16)
__device__ __forceinline__ void dma16(const ushort* g, ushort* l) {
    __builtin_amdgcn_global_load_lds(
        (const __attribute__((address_space(1))) unsigned*)g,
        (__attribute__((address_space(3))) unsigned*)l, 16, 0, 0);
}

// ---------------------------------------------------------------------------
// h-slab layout (fp16):
//   hb[t][grp(8)][cc(16)][k(512)] half     grp = bblk*2 + dir; cc = b&15; k = j
// ---------------------------------------------------------------------------
#define SLAB_ ((size_t)16 * 512)          // halves per (t,grp)
__device__ __forceinline__ size_t slab_off(int t, int grp) {
    return (size_t)(t * 8 + grp) * SLAB_;
}

// ---------------------------------------------------------------------------
// Frag-order conversions (verified 16x16x32 maps):
//   A-frag: lane l -> row = base + (l&15), k = ks*32 + (l>>4)*8 + e
//   B-frag: lane l -> col = base + (l&15), same k map
// ---------------------------------------------------------------------------

// Wi fp32 [2048][512] -> WiF fp16 frag order (128 row tiles of 16)
__global__ __launch_bounds__(256) void wif_k(
    const float* __restrict__ Wi, ushort* __restrict__ WiF)
{
    int i = blockIdx.x * 256 + threadIdx.x;   // 131,072
    int nt = i >> 10, ks = (i >> 6) & 15, l = i & 63;
    int n = nt * 16 + (l & 15);
    int k = ks * 32 + ((l >> 4) << 3);
    const float* src = Wi + (size_t)n * E_ + k;
    float4 v0 = *(const float4*)src, v1 = *(const float4*)(src + 4);
    ushort o[8] = {f2h(v0.x), f2h(v0.y), f2h(v0.z), f2h(v0.w),
                   f2h(v1.x), f2h(v1.y), f2h(v1.z), f2h(v1.w)};
    *(ushort4*)(WiF + (size_t)i * 8)     = *(ushort4*)&o[0];
    *(ushort4*)(WiF + (size_t)i * 8 + 4) = *(ushort4*)&o[4];
}

// Wh fp32 -> WhF fp16 A-frag order for the 8-WG persist decomposition:
//   [wgin(8)][w(4)][rt(4)][ks(16)][l(64)][e(8)]
//   lane l: r=l&15 -> g=r&3, j = wgin*64 + w*16 + rt*4 + (r>>2)
//   k = ks*32 + (l>>4)*8 + e
__global__ __launch_bounds__(256) void whf_k(
    const float* __restrict__ Wh, ushort* __restrict__ WhF)
{
    int i = blockIdx.x * 256 + threadIdx.x;       // 1,048,576
    int e = i & 7, l = (i >> 3) & 63, ks = (i >> 9) & 15;
    int rt = (i >> 13) & 3, w = (i >> 15) & 3, wgin = i >> 17;
    int r = l & 15, g = r & 3;
    int j = wgin * 64 + w * 16 + rt * 4 + (r >> 2);
    int k = ks * 32 + ((l >> 4) << 3) + e;
    WhF[i] = f2h(Wh[(size_t)(g * H_ + j) * H_ + k]);
}

// layer-0 input: x fp32 [16384][512] -> inF fp16 B-frag order
__global__ __launch_bounds__(256) void cvt_x_k(
    const float* __restrict__ x, ushort* __restrict__ inF)
{
    int i = blockIdx.x * 256 + threadIdx.x;   // 1,048,576
    int mt = i >> 10, ks = (i >> 6) & 15, l = i & 63;
    int m = mt * 16 + (l & 15);
    int k = ks * 32 + ((l >> 4) << 3);
    const float* src = x + (size_t)m * E_ + k;
    float4 v0 = *(const float4*)src, v1 = *(const float4*)(src + 4);
    ushort o[8] = {f2h(v0.x), f2h(v0.y), f2h(v0.z), f2h(v0.w),
                   f2h(v1.x), f2h(v1.y), f2h(v1.z), f2h(v1.w)};
    *(ushort4*)(inF + (size_t)i * 8)     = *(ushort4*)&o[0];
    *(ushort4*)(inF + (size_t)i * 8 + 4) = *(ushort4*)&o[4];
}

// layer>=1 input: inF = hsF + hsB from fp16 slabs
__global__ __launch_bounds__(256) void cvt_hs_k(
    const ushort* __restrict__ hb, ushort* __restrict__ inF)
{
    int i = blockIdx.x * 256 + threadIdx.x;   // 1,048,576
    int mt = i >> 10, ks = (i >> 6) & 15, l = i & 63;
    int m = mt * 16 + (l & 15);
    int k = ks * 32 + ((l >> 4) << 3);
    int t = m >> 6, b = m & 63, cc = b & 15, bb = b >> 4;
    const ushort* pF = hb + slab_off(t, bb * 2 + 0) + (size_t)cc * 512 + k;
    const ushort* pB = hb + slab_off(t, bb * 2 + 1) + (size_t)cc * 512 + k;
    ushort4 f0 = *(const ushort4*)pF, f1 = *(const ushort4*)(pF + 4);
    ushort4 b0 = *(const ushort4*)pB, b1 = *(const ushort4*)(pB + 4);
    ushort o[8] = {f2h(h2f(f0.x) + h2f(b0.x)), f2h(h2f(f0.y) + h2f(b0.y)),
                   f2h(h2f(f0.z) + h2f(b0.z)), f2h(h2f(f0.w) + h2f(b0.w)),
                   f2h(h2f(f1.x) + h2f(b1.x)), f2h(h2f(f1.y) + h2f(b1.y)),
                   f2h(h2f(f1.z) + h2f(b1.z)), f2h(h2f(f1.w) + h2f(b1.w))};
    *(ushort4*)(inF + (size_t)i * 8)     = *(ushort4*)&o[0];
    *(ushort4*)(inF + (size_t)i * 8 + 4) = *(ushort4*)&o[4];
}

// ---------------------------------------------------------------------------
// pre = Wi . in + bias via fp16 MFMA.  C[n(2048)][m(16384)], K=512.
// ---------------------------------------------------------------------------
__global__ __launch_bounds__(256) void gemm_mfma_k(
    const ushort* __restrict__ WiF,
    const ushort* __restrict__ inF,
    const float* __restrict__ bias,
    float* __restrict__ pre)
{
    const int tid = threadIdx.x;
    const int w   = tid >> 6;
    const int l   = tid & 63;
    const int nb  = blockIdx.x >> 6;
    const int mb  = blockIdx.x & 63;

    f32x4 acc[4][4];
#pragma unroll
    for (int i = 0; i < 4; ++i)
#pragma unroll
        for (int j = 0; j < 4; ++j) acc[i][j] = f32x4{0.f, 0.f, 0.f, 0.f};

    const ushort* aB = WiF + ((size_t)(nb * 4) * 16) * 512 + l * 8;
    const ushort* bB = inF + ((size_t)(mb * 16 + w * 4) * 16) * 512 + l * 8;

    for (int ks = 0; ks < 16; ++ks) {
        f16x8 af[4], bf[4];
#pragma unroll
        for (int i = 0; i < 4; ++i)
            af[i] = *(const f16x8*)(aB + ((size_t)i * 16 + ks) * 512);
#pragma unroll
        for (int j = 0; j < 4; ++j)
            bf[j] = *(const f16x8*)(bB + ((size_t)j * 16 + ks) * 512);
#pragma unroll
        for (int i = 0; i < 4; ++i)
#pragma unroll
            for (int j = 0; j < 4; ++j)
                acc[i][j] = __builtin_amdgcn_mfma_f32_16x16x32_f16(
                    af[i], bf[j], acc[i][j], 0, 0, 0);
    }

#pragma unroll
    for (int i = 0; i < 4; ++i) {
#pragma unroll
        for (int j = 0; j < 4; ++j) {
#pragma unroll
            for (int g = 0; g < 4; ++g) {
                int n = nb * 64 + i * 16 + ((l >> 4) << 2) + g;
                int m = mb * 256 + w * 64 + j * 16 + (l & 15);
                int t = m >> 6, b = m & 63;
                pre[((size_t)t * G4_ + n) * B_ + b] = acc[i][j][g] + bias[n];
            }
        }
    }
}

// ---------------------------------------------------------------------------
// Persistent recurrence v12: 8 WGs/group, wave-autonomous, zero barriers.
// 64 WGs: grp = bid&7 (sync domain, XCD-local slab under %8 round-robin;
// perf-only), wgin = bid>>3 (0..7, 64 j-columns each). Wave w owns 16 j
// (4 row-tiles); per thread FOUR (j,ch) chains (rt x lane map as whf_k).
// Per step per wave (no __syncthreads anywhere):
//   pre C-in loads -> poll 32 per-WAVE flags (lane-parallel) -> DMA whole
//   16KB slab into this wave's PRIVATE LDS quadrant (16 issues) -> vmcnt(0)
//   -> 64 MFMAs (4 indep chains share each B-frag) -> gates x4 -> publish
//   (4 pair-words per even-q lane, write-through) -> vmcnt(0) -> own flag.
// Protocol semantics (first-touch slab, relaxed agent) proven R4-R12.
// ---------------------------------------------------------------------------
__global__ __launch_bounds__(256, 1) void lstm_persist_k(
    const float* __restrict__ pre,    // [S][G4][B]
    const ushort* __restrict__ WhF,   // frag-ordered fp16 weights
    ushort* __restrict__ hb,          // h slabs [S][8][16][512] fp16
    unsigned* __restrict__ flg)       // [8][S][32] per-wave flags, zeroed
{
    __shared__ ushort hS[4][8192];    // 16KB private per wave

    const int tid  = threadIdx.x;
    const int grp  = blockIdx.x & 7;
    const int wgin = blockIdx.x >> 3;            // 0..7
    const int dir  = grp & 1;
    const int bblk = grp >> 1;
    const int w    = tid >> 6;                   // wave
    const int l    = tid & 63;
    const int ch   = l & 15;
    const int q    = l >> 4;                     // 0..3
    const int jb   = wgin * 64 + w * 16;         // wave's j base

    ushort* myLDS = hS[w];
    const ushort* wbase = WhF + ((size_t)(wgin * 4 + w) << 15) + (l << 3);
    const int dmaLane = (l & 15) * 512 + (q << 3);

    // preload wave's weight slice: 4 row-tiles x 16 ks (256 VGPRs nominal)
    f16x8 wF[4][16];
#pragma unroll
    for (int rt = 0; rt < 4; ++rt)
#pragma unroll
        for (int ks = 0; ks < 16; ++ks)
            wF[rt][ks] = *(const f16x8*)(wbase + (((rt << 4) + ks) << 9));

    float c[4] = {0.f, 0.f, 0.f, 0.f};

    for (int t = 0; t < S_; ++t) {
        const int tf = dir ? (S_ - 1 - t) : t;

        // C-in from pre (16 loads, issued before the poll to hide latency)
        f32x4 acc[4];
#pragma unroll
        for (int rt = 0; rt < 4; ++rt)
#pragma unroll
            for (int g = 0; g < 4; ++g)
                acc[rt][g] = pre[((size_t)tf * G4_ + g * H_ + jb + rt * 4 + q)
                                 * B_ + bblk * 16 + ch];

        if (t > 0) {
            // poll the group's 32 per-wave flags (lane-parallel)
            const unsigned* fb = &flg[((size_t)grp * S_ + (t - 1)) * 32];
            unsigned guard = 0;
            for (;;) {
                unsigned f = __hip_atomic_load(&fb[l & 31], __ATOMIC_RELAXED,
                                               __HIP_MEMORY_SCOPE_AGENT);
                if (__all(f != 0)) break;
                if (++guard > (1u << 18)) break;   // fail visibly, don't hang
            }

            // DMA whole slab(t-1) into this wave's private LDS quadrant
            const int tfp = dir ? (tf + 1) : (tf - 1);
            const ushort* slab = hb + slab_off(tfp, grp);
#pragma unroll
            for (int ks = 0; ks < 16; ++ks)
                dma16(slab + ks * 32 + dmaLane, myLDS + ks * 512);
            asm volatile("s_waitcnt vmcnt(0)" ::: "memory");
            __builtin_amdgcn_sched_barrier(0);

            // 64 MFMAs: 4 independent row-tile chains share each B-frag
#pragma unroll
            for (int ks = 0; ks < 16; ++ks) {
                f16x8 bf = *(const f16x8*)&myLDS[(ks << 9) + (l << 3)];
                acc[0] = __builtin_amdgcn_mfma_f32_16x16x32_f16(wF[0][ks], bf, acc[0], 0, 0, 0);
                acc[1] = __builtin_amdgcn_mfma_f32_16x16x32_f16(wF[1][ks], bf, acc[1], 0, 0, 0);
                acc[2] = __builtin_amdgcn_mfma_f32_16x16x32_f16(wF[2][ks], bf, acc[2], 0, 0, 0);
                acc[3] = __builtin_amdgcn_mfma_f32_16x16x32_f16(wF[3][ks], bf, acc[3], 0, 0, 0);
            }
        }

        // gates (i,f,o,g) for the thread's 4 chains; publish fp16 pairs
        unsigned* shW = (unsigned*)(hb + slab_off(tf, grp));
#pragma unroll
        for (int rt = 0; rt < 4; ++rt) {
            float si = fsigmoid(acc[rt][0]);
            float sf = fsigmoid(acc[rt][1]);
            float so = fsigmoid(acc[rt][2]);
            float tg = ftanh_(acc[rt][3]);
            c[rt] = fmaf(sf, c[rt], si * tg);
            float h = so * ftanh_(c[rt]);

            unsigned hv = f2h(h);
            unsigned pv = (unsigned)__shfl_xor((int)hv, 16);  // partner q^1
            if ((q & 1) == 0) {
                unsigned pair = (hv & 0xFFFFu) | (pv << 16);
                int j = jb + rt * 4 + q;
                __hip_atomic_store(&shW[(size_t)ch * 256 + (j >> 1)], pair,
                                   __ATOMIC_RELAXED, __HIP_MEMORY_SCOPE_AGENT);
            }
        }

        // drain this wave's publishes, then raise this wave's flag
        asm volatile("s_waitcnt vmcnt(0)" ::: "memory");
        if (l == 0)
            __hip_atomic_store(&flg[((size_t)grp * S_ + t) * 32 + wgin * 4 + w],
                               1u, __ATOMIC_RELAXED, __HIP_MEMORY_SCOPE_AGENT);
    }
}

// out[t][b][e] = hF + hB from fp16 slabs
__global__ __launch_bounds__(256) void t4_to_row_k(
    const ushort* __restrict__ hb, float* __restrict__ out)
{
    int i  = blockIdx.x * 256 + threadIdx.x;   // 2,097,152 float4 units
    int e4 = i & (E4_ - 1);
    int b  = (i >> 7) & 63;
    int t  = i >> 13;
    int cc = b & 15, bb = b >> 4;
    size_t e = (size_t)cc * 512 + e4 * 4;
    ushort4 hF = *(const ushort4*)(hb + slab_off(t, bb * 2 + 0) + e);
    ushort4 hB = *(const ushort4*)(hb + slab_off(t, bb * 2 + 1) + e);
    float4 v = make_float4(h2f(hF.x) + h2f(hB.x), h2f(hF.y) + h2f(hB.y),
                           h2f(hF.z) + h2f(hB.z), h2f(hF.w) + h2f(hB.w));
    *(float4*)&out[((size_t)(t * B_ + b)) * E_ + e4 * 4] = v;
}

// tail [b][j] = h_fwd(tf=255) + h_bwd(tf=0)
__global__ __launch_bounds__(256) void tail_k(
    const ushort* __restrict__ hb, float* __restrict__ out2)
{
    int i = blockIdx.x * 256 + threadIdx.x;   // 32768
    int b = i >> 9, j = i & 511;
    int cc = b & 15, bb = b >> 4;
    ushort hF = hb[slab_off(255, bb * 2 + 0) + (size_t)cc * 512 + j];
    ushort hB = hb[slab_off(0,   bb * 2 + 1) + (size_t)cc * 512 + j];
    out2[i] = h2f(hF) + h2f(hB);
}

// ---------------------------------------------------------------------------
// Workspace (bytes):
//   pre : 128 MiB   hb : 32 MiB   flg : 1 MiB   WhF4 : 8 MiB
//   WiF4 : 8 MiB    inF : 16 MiB                total ~193 MiB
// ---------------------------------------------------------------------------
extern "C" void kernel_launch(void* const* d_in, const int* in_sizes, int n_in,
                              void* d_out, int out_size, void* d_ws, size_t ws_size,
                              hipStream_t stream) {
    const float* x    = (const float*)d_in[0];
    const float* Wi   = (const float*)d_in[1];
    const float* Wh   = (const float*)d_in[2];
    const float* bias = (const float*)d_in[3];
    float* out = (float*)d_out;

    float* ws  = (float*)d_ws;
    float* pre = ws;
    ushort* hb   = (ushort*)(pre + (size_t)S_ * G4_ * B_);   // 16.8M halves
    unsigned* flg = (unsigned*)(hb + (size_t)S_ * 8 * SLAB_); // 8*256*32 u32
    ushort* WhF4 = (ushort*)(flg + (size_t)8 * S_ * 32);
    ushort* WiF4 = WhF4 + (size_t)4 * 1024 * 1024;
    ushort* inF  = WiF4 + (size_t)4 * 1024 * 1024;

    // one-time weight conversions (all layers)
    for (int l = 0; l < NL_; ++l) {
        whf_k<<<4096, 256, 0, stream>>>(Wh + (size_t)l * G4_ * H_,
                                        WhF4 + (size_t)l * 1024 * 1024);
        wif_k<<<512, 256, 0, stream>>>(Wi + (size_t)l * G4_ * E_,
                                       WiF4 + (size_t)l * 1024 * 1024);
    }

    for (int l = 0; l < NL_; ++l) {
        if (l == 0) cvt_x_k<<<4096, 256, 0, stream>>>(x, inF);
        else        cvt_hs_k<<<4096, 256, 0, stream>>>(hb, inF);
        gemm_mfma_k<<<2048, 256, 0, stream>>>(WiF4 + (size_t)l * 1024 * 1024,
                                              inF, bias + (size_t)l * G4_, pre);
        hipMemsetAsync(flg, 0, (size_t)8 * S_ * 32 * sizeof(unsigned), stream);
        lstm_persist_k<<<64, 256, 0, stream>>>(
            pre, WhF4 + (size_t)l * 1024 * 1024, hb, flg);
    }
    t4_to_row_k<<<8192, 256, 0, stream>>>(hb, out);
    tail_k<<<128, 256, 0, stream>>>(hb, out + (size_t)S_ * B_ * H_);
}